// Round 7
// baseline (1517.297 us; speedup 1.0000x reference)
//
#include <hip/hip_runtime.h>

#define BATCH 32
#define NPTS  262144
#define KSAMP 256
#define NF    10
#define INDIM 60
#define HID   768

// Split-block dual-domain FPS: 256 blocks x 1024 threads (proven coop config).
// Each block = TWO independent 512-thread halves working on DIFFERENT batches
// (16 slices/batch). While half A waits in its cross-CU rendezvous, half B's
// waves fill the SIMDs (anti-phase locked by a one-time s_sleep stagger).
#define NSLICE 16
#define TPB_H  512
#define SLICE  (NPTS/NSLICE)      // 16384 pts per slice
#define GPTS   (TPB_H*4)          // 2048 pts per group
// per-thread: 32 pts = 8 groups of 4: j=0..3 regs, j=4..6 LDS, j=7 global SoA
#define REG_G 4
#define LDS_G 3

#define PI_F 3.14159274101257324f  // float(math.pi)
#define PAY56 0x00FFFFFFFFFFFFFFull

typedef float v2f __attribute__((ext_vector_type(2)));

// Static device scratch (rewritten every call before use)
__device__ float g_px[BATCH*NPTS];   // only group j=7 regions used
__device__ float g_py[BATCH*NPTS];
__device__ float g_pz[BATCH*NPTS];
__device__ float g_samp[BATCH*KSAMP*3];
__device__ float g_enc[(size_t)BATCH*KSAMP*INDIM];
__device__ float g_Wt[INDIM*HID];
// ONE tagged u64 per [parity][slice] (r4/r5 lesson: multi-word slots explode
// fabric traffic). 16 slices = 128 B per parity (2 lines) — polls throttled.
__device__ unsigned long long g_slot[BATCH][2][NSLICE];

__device__ __forceinline__ float san(float v){
  float m = v*0.0f;                 // finite -> 0, inf/nan -> nan (no fast-math fold)
  return (m == 0.0f) ? v : 0.0f;
}

__device__ __forceinline__ unsigned long long shfl64_xor(unsigned long long v, int m){
  unsigned lo = __shfl_xor((unsigned)v, m);
  unsigned hi = __shfl_xor((unsigned)(v>>32), m);
  return ((unsigned long long)hi<<32)|lo;
}
__device__ __forceinline__ unsigned long long shfl64(unsigned long long v, int src){
  unsigned lo = __shfl((unsigned)v, src);
  unsigned hi = __shfl((unsigned)(v>>32), src);
  return ((unsigned long long)hi<<32)|lo;
}

// ---------------- region prepass: sanitize + SoA for global-resident 1/8 ----------------
__global__ __launch_bounds__(256) void region_prepass(const float* __restrict__ pc){
  int bid = blockIdx.x;             // 1024 blocks
  int b   = bid >> 5;               // 32 blocks per batch
  int rem = bid & 31;
  int q   = rem*1024 + threadIdx.x*4;   // 0..32767 region-local (per batch)
  int s   = q >> 11;                    // slice (2048 pts of group 7 per slice)
  int o   = q & 2047;
  int p   = s*SLICE + 7*GPTS + o;       // global point index in batch
  const float* src = pc + ((size_t)b*NPTS + p)*3;
  float4 A = *(const float4*)(src);
  float4 Bv= *(const float4*)(src+4);
  float4 C = *(const float4*)(src+8);
  float v[12] = {A.x,A.y,A.z,A.w,Bv.x,Bv.y,Bv.z,Bv.w,C.x,C.y,C.z,C.w};
#pragma unroll
  for (int j=0;j<12;j++) v[j] = san(v[j]);
  size_t base = (size_t)b*NPTS + p;
  *(float4*)(g_px+base) = make_float4(v[0],v[3],v[6],v[9]);
  *(float4*)(g_py+base) = make_float4(v[1],v[4],v[7],v[10]);
  *(float4*)(g_pz+base) = make_float4(v[2],v[5],v[8],v[11]);
}

// ---------------- W transpose + slot clear ----------------
__global__ __launch_bounds__(256) void wtrans(const float* __restrict__ W){
  int idx = blockIdx.x*256 + threadIdx.x;   // < 60*768 = 46080
  int d = idx / HID;
  int h = idx - d*HID;
  g_Wt[idx] = W[h*INDIM + d];
  if (blockIdx.x == 0){
    // clear all 32*2*16 = 1024 slot words (stale tags could alias tag==k)
#pragma unroll
    for (int r=0;r<4;r++)
      ((unsigned long long*)g_slot)[threadIdx.x + 256*r] = 0ull;
  }
}

// ---------------- FPS ----------------
__global__ __attribute__((amdgpu_flat_work_group_size(1024,1024)))
           __attribute__((amdgpu_waves_per_eu(4,4)))
void fps_kernel(const float* __restrict__ pc){
#pragma clang fp contract(off)
  // contract(off): distance chain must stay mul+add (rn each step, no FMA
  // fusion) to be bit-exact vs the reference reduction.
  __shared__ float4 sX[2*LDS_G*TPB_H], sY[2*LDS_G*TPB_H], sZ[2*LDS_G*TPB_H]; // 144 KB
  __shared__ unsigned long long s_cand[2][2][8];  // [half][parity][wave-in-half]
  __shared__ float s_res[2][2][4];                // [half][parity] winner coords
  __shared__ int   s_flag[2][2];                  // [half][parity] iteration flag

  // Mapping (XCD-locality, round-robin blockIdx%8 -> XCD assumption):
  //   XCD x hosts batches 4x..4x+3. Half A: batches 4x..4x+1; half B: 4x+2..4x+3.
  //   Each batch's 16 slices live on 16 distinct CUs within the XCD.
  const int blk = blockIdx.x;                 // 0..255
  const int xcd = blk & 7;
  const int jj  = blk >> 3;                   // 0..31
  const int tid = threadIdx.x;
  const int half  = tid >> 9;                 // 0 = waves 0-7, 1 = waves 8-15
  const int tid_h = tid & 511;
  const int lane  = tid & 63;
  const int wv    = (tid >> 6) & 7;           // wave within half
  const int s   = jj & 15;                    // slice
  const int b   = 4*xcd + (jj >> 4) + 2*half; // batch (A/B differ!)
  const size_t bN = (size_t)b*NPTS;
  const int soff = s*SLICE;

  // ---- one-time load: regs (j=0..3, packed pairs) and LDS (j=4..6) ----
  v2f rx2[REG_G*2], ry2[REG_G*2], rz2[REG_G*2];   // pair p covers pts 2p,2p+1
#pragma unroll
  for (int j=0;j<REG_G+LDS_G;j++){
    int p0 = soff + j*GPTS + tid_h*4;
    const float* src = pc + (bN + p0)*3;
    float4 A = *(const float4*)(src);
    float4 Bv= *(const float4*)(src+4);
    float4 C = *(const float4*)(src+8);
    float v[12] = {A.x,A.y,A.z,A.w,Bv.x,Bv.y,Bv.z,Bv.w,C.x,C.y,C.z,C.w};
#pragma unroll
    for (int q=0;q<12;q++) v[q] = san(v[q]);
    if (j < REG_G){
      rx2[j*2+0] = (v2f){v[0], v[3]};  rx2[j*2+1] = (v2f){v[6], v[9]};
      ry2[j*2+0] = (v2f){v[1], v[4]};  ry2[j*2+1] = (v2f){v[7], v[10]};
      rz2[j*2+0] = (v2f){v[2], v[5]};  rz2[j*2+1] = (v2f){v[8], v[11]};
    } else {
      int li = (half*LDS_G + (j-REG_G))*TPB_H + tid_h;
      sX[li] = make_float4(v[0],v[3],v[6],v[9]);
      sY[li] = make_float4(v[1],v[4],v[7],v[10]);
      sZ[li] = make_float4(v[2],v[5],v[8],v[11]);
    }
  }

  float d[32];
#pragma unroll
  for (int i=0;i<32;i++) d[i] = __builtin_huge_valf();

  // first sample = sanitized point 0 of this half's batch
  float lx = san(pc[bN*3+0]), ly = san(pc[bN*3+1]), lz = san(pc[bN*3+2]);
  if (s==0 && tid_h<3) g_samp[(size_t)b*KSAMP*3 + tid_h] = san(pc[bN*3 + tid_h]);
  if (tid < 4)  ((int*)s_flag)[tid] = 0;
  if (tid < 32) ((unsigned long long*)s_cand)[tid] = 0ull;
  __syncthreads();   // LDS coords + flags visible; the ONLY block barrier

  // anti-phase stagger: half B starts ~4000 cyc late, so B computes while A
  // waits in its rendezvous and vice versa (each batch's own rendezvous keeps
  // its 16 slices phase-coherent thereafter).
  if (half) __builtin_amdgcn_s_sleep(62);

  const size_t gb = bN + soff + (size_t)7*GPTS + tid_h*4;   // loop-invariant

  for (int k=1; k<KSAMP; k++){
    const int par = k & 1;
    const unsigned long long tagk = (unsigned long long)(unsigned)k << 56;
    // issue global-group loads first (L2-resident region)
    float4 gx = *(const float4*)(g_px+gb);
    float4 gy = *(const float4*)(g_py+gb);
    float4 gz = *(const float4*)(g_pz+gb);

    // broadcast last sample into packed form
    v2f l2x = (v2f){lx,lx}, l2y = (v2f){ly,ly}, l2z = (v2f){lz,lz};

    float bestv = -1.0f; int bestc = 0;   // 5-bit slot code

    // packed distance for a PAIR of points (codes DI, DI+1); scalar tracking in
    // ascending index order preserves the first-max tie-break. pk ops are IEEE
    // rn per half == bit-exact vs the scalar __f*_rn chain.
#define UPD2(X2,Y2,Z2, DI) { \
      v2f dx_ = (X2) - l2x, dy_ = (Y2) - l2y, dz_ = (Z2) - l2z; \
      v2f dd_ = ((dx_*dx_) + (dy_*dy_)) + (dz_*dz_); \
      float nd0_ = fminf(d[DI], dd_.x);  d[DI] = nd0_; \
      if (nd0_ > bestv){ bestv = nd0_; bestc = (DI); } \
      float nd1_ = fminf(d[(DI)+1], dd_.y);  d[(DI)+1] = nd1_; \
      if (nd1_ > bestv){ bestv = nd1_; bestc = (DI)+1; } }

    // register groups j=0..3 (codes 0..15)
#pragma unroll
    for (int p=0;p<REG_G*2;p++)
      UPD2(rx2[p], ry2[p], rz2[p], p*2)
    // LDS groups j=4..6 (codes 16..27)
#pragma unroll
    for (int j=0;j<LDS_G;j++){
      int li = (half*LDS_G + j)*TPB_H + tid_h;
      float4 X = sX[li], Y = sY[li], Z = sZ[li];
      v2f Xa=(v2f){X.x,X.y}, Xb=(v2f){X.z,X.w};
      v2f Ya=(v2f){Y.x,Y.y}, Yb=(v2f){Y.z,Y.w};
      v2f Za=(v2f){Z.x,Z.y}, Zb=(v2f){Z.z,Z.w};
      UPD2(Xa, Ya, Za, (REG_G+j)*4)
      UPD2(Xb, Yb, Zb, (REG_G+j)*4+2)
    }
    // global group j=7 (codes 28..31)
    {
      v2f Xa=(v2f){gx.x,gx.y}, Xb=(v2f){gx.z,gx.w};
      v2f Ya=(v2f){gy.x,gy.y}, Yb=(v2f){gy.z,gy.w};
      v2f Za=(v2f){gz.x,gz.y}, Zb=(v2f){gz.z,gz.w};
      UPD2(Xa, Ya, Za, 28)
      UPD2(Xb, Yb, Zb, 30)
    }
#undef UPD2

    // code -> batch-local index (ascending scan preserves first-max tie-break)
    int besti = soff + ((bestc>>2)<<11) + (tid_h<<2) + (bestc&3);

    // intra-wave argmax (first-index tie-break)
#pragma unroll
    for (int off=32; off; off>>=1){
      float ov = __shfl_down(bestv, off);
      int   oi = __shfl_down(besti, off);
      if (ov > bestv || (ov == bestv && oi < besti)){ bestv=ov; besti=oi; }
    }
    // per-wave candidate publish: tagged u64 [k:8][val:32][0xFFFFFF^idx:24]
    unsigned long long wkey = tagk
                            | ((unsigned long long)__float_as_uint(bestv) << 24)
                            | (unsigned long long)(0xFFFFFFu ^ (unsigned)besti);
    if (lane==0)
      __hip_atomic_store(&s_cand[half][par][wv], wkey,
                         __ATOMIC_RELAXED, __HIP_MEMORY_SCOPE_WORKGROUP);

    if (wv==0){
      // gather this half's 8 wave candidates (all lanes poll [lane&7] — LDS
      // broadcast, keeps the butterfly uniform); s_sleep stays off the other
      // half's issue slots.
      unsigned long long pay;
      for (;;){
        pay = __hip_atomic_load(&s_cand[half][par][lane & 7],
                                __ATOMIC_RELAXED, __HIP_MEMORY_SCOPE_WORKGROUP);
        if ((unsigned)(pay >> 56) == (unsigned)k) break;
        __builtin_amdgcn_s_sleep(1);
      }
      pay &= PAY56;
#pragma unroll
      for (int m=1; m<8; m<<=1){
        unsigned long long o = shfl64_xor(pay, m);
        if (o > pay) pay = o;
      }
      // publish block-half candidate (1 tagged word)
      if (lane==0)
        __hip_atomic_store(&g_slot[b][par][s], tagk | pay,
                           __ATOMIC_RELAXED, __HIP_MEMORY_SCOPE_AGENT);
      // poll the 16 slices' slots (lanes poll [lane&15]); s_sleep(2) throttles
      // fabric traffic on the 2-line slot region (r4/r5 congestion lesson).
      unsigned long long gpay;
      for (;;){
        gpay = __hip_atomic_load(&g_slot[b][par][lane & 15],
                                 __ATOMIC_RELAXED, __HIP_MEMORY_SCOPE_AGENT);
        if ((unsigned)(gpay >> 56) == (unsigned)k) break;
        __builtin_amdgcn_s_sleep(2);
      }
      __builtin_amdgcn_s_setprio(1);
      gpay &= PAY56;
#pragma unroll
      for (int m=1; m<16; m<<=1){
        unsigned long long o = shfl64_xor(gpay, m);
        if (o > gpay) gpay = o;
      }
      unsigned long long wing = shfl64(gpay, 0);
      unsigned w = 0xFFFFFFu ^ (unsigned)(wing & 0xFFFFFFu);   // batch-local idx
      int wu = __builtin_amdgcn_readfirstlane((int)w);         // uniform -> scalar
      if (lane < 3){
        float cv = san(pc[(bN + (size_t)(unsigned)wu)*3 + lane]);
        s_res[half][par][lane] = cv;
        if (s==0) g_samp[((size_t)b*KSAMP + k)*3 + lane] = cv;
      }
      // release: s_res writes ordered before flag (workgroup scope)
      if (lane==0)
        __hip_atomic_store(&s_flag[half][par], k,
                           __ATOMIC_RELEASE, __HIP_MEMORY_SCOPE_WORKGROUP);
      __builtin_amdgcn_s_setprio(0);
      lx = s_res[half][par][0]; ly = s_res[half][par][1]; lz = s_res[half][par][2];
    } else {
      // data-driven wait; s_sleep keeps the spin off the other half's slots.
      while (__hip_atomic_load(&s_flag[half][par],
                               __ATOMIC_ACQUIRE, __HIP_MEMORY_SCOPE_WORKGROUP) != k)
        __builtin_amdgcn_s_sleep(1);
      lx = s_res[half][par][0]; ly = s_res[half][par][1]; lz = s_res[half][par][2];
    }
  }
}

// ---------------- normalize + Fourier encode ----------------
template<int OP>  // 0 sum, 1 max, 2 min
__device__ __forceinline__ float blk_red(float v, float* s4){
  int tid = threadIdx.x;
#pragma unroll
  for (int off=32; off; off>>=1){
    float o = __shfl_down(v, off);
    v = (OP==0) ? v+o : ((OP==1) ? fmaxf(v,o) : fminf(v,o));
  }
  if ((tid&63)==0) s4[tid>>6] = v;
  __syncthreads();
  float r0=s4[0], r1=s4[1], r2=s4[2], r3=s4[3];
  float r = (OP==0) ? ((r0+r1)+(r2+r3))
          : ((OP==1) ? fmaxf(fmaxf(r0,r1),fmaxf(r2,r3))
                     : fminf(fminf(r0,r1),fminf(r2,r3)));
  __syncthreads();
  return r;
}

__global__ __launch_bounds__(256) void norm_encode(){
  __shared__ float s4[4];
  int b = blockIdx.x, k = threadIdx.x;
  const float* sp = &g_samp[((size_t)b*KSAMP + k)*3];
  float x = sp[0], y = sp[1], z = sp[2];

  float cx = blk_red<0>(x, s4) * (1.0f/KSAMP);
  float cy = blk_red<0>(y, s4) * (1.0f/KSAMP);
  float cz = blk_red<0>(z, s4) * (1.0f/KSAMP);

  float ux = __fsub_rn(x,cx), uy = __fsub_rn(y,cy), uz = __fsub_rn(z,cz);

  float mxx = blk_red<1>(ux, s4), mnx = blk_red<2>(ux, s4);
  float mxy = blk_red<1>(uy, s4), mny = blk_red<2>(uy, s4);
  float mxz = blk_red<1>(uz, s4), mnz = blk_red<2>(uz, s4);
  float bx = __fsub_rn(mxx,mnx), by = __fsub_rn(mxy,mny), bz = __fsub_rn(mxz,mnz);
  float md = fmaxf(fmaxf(bx,by),bz);
  float scale = (md > 1e-8f) ? md : 1.0f;

  float n3[3] = { __fdiv_rn(ux,scale), __fdiv_rn(uy,scale), __fdiv_rn(uz,scale) };

  float* e = &g_enc[((size_t)b*KSAMP + k)*INDIM];
#pragma unroll
  for (int c=0;c<3;c++){
    float base = n3[c];
#pragma unroll
    for (int f=0; f<NF; f++){
      float t = __fmul_rn(base, (float)(1<<f));
      float a = __fmul_rn(t, PI_F);
      e[c*2*NF + f*2 + 0] = sinf(a);
      e[c*2*NF + f*2 + 1] = cosf(a);
    }
  }
}

// ---------------- GEMM ----------------
__global__ __launch_bounds__(256) void gemm_kernel(const float* __restrict__ bias,
                                                   float* __restrict__ out){
  __shared__ float s_enc[4*INDIM];
  int blk = blockIdx.x, tid = threadIdx.x;
  int row0 = blk*4;                         // 4 (b,k) rows per block
  if (tid < 4*INDIM) s_enc[tid] = g_enc[(size_t)row0*INDIM + tid];
  __syncthreads();

  float acc[4][3] = {};
  for (int d=0; d<INDIM; d++){
    float w0 = g_Wt[d*HID + tid];
    float w1 = g_Wt[d*HID + tid + 256];
    float w2 = g_Wt[d*HID + tid + 512];
#pragma unroll
    for (int r=0;r<4;r++){
      float ev = s_enc[r*INDIM + d];
      acc[r][0] = fmaf(ev, w0, acc[r][0]);
      acc[r][1] = fmaf(ev, w1, acc[r][1]);
      acc[r][2] = fmaf(ev, w2, acc[r][2]);
    }
  }
  float b0=bias[tid], b1=bias[tid+256], b2=bias[tid+512];
#pragma unroll
  for (int r=0;r<4;r++){
    size_t o = (size_t)(row0+r)*HID;
    out[o+tid]     = acc[r][0]+b0;
    out[o+tid+256] = acc[r][1]+b1;
    out[o+tid+512] = acc[r][2]+b2;
  }
}

// ---------------- launch ----------------
extern "C" void kernel_launch(void* const* d_in, const int* in_sizes, int n_in,
                              void* d_out, int out_size, void* d_ws, size_t ws_size,
                              hipStream_t stream){
  const float* pc   = (const float*)d_in[0];
  const float* W    = (const float*)d_in[1];
  const float* bias = (const float*)d_in[2];
  float* out = (float*)d_out;

  region_prepass<<<1024, 256, 0, stream>>>(pc);
  wtrans        <<<(INDIM*HID)/256, 256, 0, stream>>>(W);

  void* args[] = { (void*)&pc };
  hipLaunchCooperativeKernel((void*)fps_kernel, dim3(BATCH*NSLICE/2), dim3(1024),
                             args, 0, stream);

  norm_encode<<<BATCH, KSAMP, 0, stream>>>();
  gemm_kernel<<<(BATCH*KSAMP)/4, 256, 0, stream>>>(bias, out);
}

// Round 8
// 1316.827 us; speedup vs baseline: 1.1522x; 1.1522x over previous
//
#include <hip/hip_runtime.h>

#define BATCH 32
#define NPTS  262144
#define KSAMP 256
#define NF    10
#define INDIM 60
#define HID   768

#define NBLK_PER_B 8
#define SLICE (NPTS/NBLK_PER_B)   // 32768 points per block (one CU)
// per-thread point layout: 8 groups of 4 pts
//   j=0..3  -> registers (16 pts)
//   j=4..6  -> LDS       (12 pts, 144 KB)
//   j=7     -> global SoA (4 pts, L2-resident)
#define REG_G 4
#define LDS_G 3

#define PI_F 3.14159274101257324f  // float(math.pi)
#define PAY56 0x00FFFFFFFFFFFFFFull

typedef float v2f __attribute__((ext_vector_type(2)));

// Static device scratch (rewritten every call before use)
__device__ float g_px[BATCH*NPTS];   // only group j=7 regions used
__device__ float g_py[BATCH*NPTS];
__device__ float g_pz[BATCH*NPTS];
__device__ float g_samp[BATCH*KSAMP*3];
__device__ float g_enc[(size_t)BATCH*KSAMP*INDIM];
__device__ float g_Wt[INDIM*HID];
// ONE tagged u64 per [parity][slice] (r4/r5 lesson: fat multi-word slots
// explode HBM traffic 150x; the whole batch's slots must stay in one line)
__device__ unsigned long long g_slot[BATCH][2][NBLK_PER_B];

__device__ __forceinline__ float san(float v){
  float m = v*0.0f;                 // finite -> 0, inf/nan -> nan (no fast-math fold)
  return (m == 0.0f) ? v : 0.0f;
}

__device__ __forceinline__ unsigned long long shfl64_xor(unsigned long long v, int m){
  unsigned lo = __shfl_xor((unsigned)v, m);
  unsigned hi = __shfl_xor((unsigned)(v>>32), m);
  return ((unsigned long long)hi<<32)|lo;
}
__device__ __forceinline__ unsigned long long shfl64(unsigned long long v, int src){
  unsigned lo = __shfl((unsigned)v, src);
  unsigned hi = __shfl((unsigned)(v>>32), src);
  return ((unsigned long long)hi<<32)|lo;
}

// ---------------- region prepass: sanitize + SoA for global-resident 1/8 ----------------
__global__ __launch_bounds__(256) void region_prepass(const float* __restrict__ pc){
  int bid = blockIdx.x;             // 1024 blocks
  int b   = bid >> 5;               // 32 blocks per batch
  int rem = bid & 31;
  int q   = rem*1024 + threadIdx.x*4;   // 0..32767 region-local (per batch)
  int s   = q >> 12;                    // slice (4096 pts of group 7 per slice)
  int o   = q & 4095;
  int p   = s*SLICE + 7*4096 + o;       // global point index in batch
  const float* src = pc + ((size_t)b*NPTS + p)*3;
  float4 A = *(const float4*)(src);
  float4 Bv= *(const float4*)(src+4);
  float4 C = *(const float4*)(src+8);
  float v[12] = {A.x,A.y,A.z,A.w,Bv.x,Bv.y,Bv.z,Bv.w,C.x,C.y,C.z,C.w};
#pragma unroll
  for (int j=0;j<12;j++) v[j] = san(v[j]);
  size_t base = (size_t)b*NPTS + p;
  *(float4*)(g_px+base) = make_float4(v[0],v[3],v[6],v[9]);
  *(float4*)(g_py+base) = make_float4(v[1],v[4],v[7],v[10]);
  *(float4*)(g_pz+base) = make_float4(v[2],v[5],v[8],v[11]);
}

// ---------------- W transpose + slot clear ----------------
__global__ __launch_bounds__(256) void wtrans(const float* __restrict__ W){
  int idx = blockIdx.x*256 + threadIdx.x;   // < 60*768 = 46080
  int d = idx / HID;
  int h = idx - d*HID;
  g_Wt[idx] = W[h*INDIM + d];
  if (blockIdx.x == 0 && threadIdx.x < 256){
    // clear all 32*2*8 = 512 slot words (stale tags could alias tag==k)
    ((unsigned long long*)g_slot)[threadIdx.x*2+0] = 0ull;
    ((unsigned long long*)g_slot)[threadIdx.x*2+1] = 0ull;
  }
}

// ---------------- FPS ----------------
__global__ __attribute__((amdgpu_flat_work_group_size(1024,1024)))
           __attribute__((amdgpu_waves_per_eu(4,4)))
void fps_kernel(const float* __restrict__ pc){
#pragma clang fp contract(off)
  // contract(off): distance chain must stay mul+add (rn each step, no FMA
  // fusion) to be bit-exact vs the reference reduction.
  __shared__ float4 sX[LDS_G*1024], sY[LDS_G*1024], sZ[LDS_G*1024];  // 144 KB
  __shared__ unsigned long long s_cand[16];  // per-wave candidate (barrier-ordered)
  __shared__ float s_res[4];                 // winner coords (barrier-ordered)

  // XCD-locality swizzle: assuming round-robin blockIdx%8 -> XCD, this puts
  // all 8 slices of a batch on ONE XCD (4 batches per XCD). Perf-only heuristic.
  const int blk = blockIdx.x;
  const int b   = (blk & 7) + 8*(blk >> 6);   // batch
  const int s   = (blk >> 3) & 7;             // slice
  const int tid = threadIdx.x;
  const int lane = tid & 63, wave = tid >> 6;
  const size_t bN = (size_t)b*NPTS;
  const int soff = s*SLICE;

  // ---- one-time load: regs (j=0..3, packed pairs) and LDS (j=4..6) ----
  v2f rx2[REG_G*2], ry2[REG_G*2], rz2[REG_G*2];   // pair p covers pts 2p,2p+1
#pragma unroll
  for (int j=0;j<REG_G+LDS_G;j++){
    int p0 = soff + j*4096 + tid*4;
    const float* src = pc + (bN + p0)*3;
    float4 A = *(const float4*)(src);
    float4 Bv= *(const float4*)(src+4);
    float4 C = *(const float4*)(src+8);
    float v[12] = {A.x,A.y,A.z,A.w,Bv.x,Bv.y,Bv.z,Bv.w,C.x,C.y,C.z,C.w};
#pragma unroll
    for (int q=0;q<12;q++) v[q] = san(v[q]);
    if (j < REG_G){
      rx2[j*2+0] = (v2f){v[0], v[3]};  rx2[j*2+1] = (v2f){v[6], v[9]};
      ry2[j*2+0] = (v2f){v[1], v[4]};  ry2[j*2+1] = (v2f){v[7], v[10]};
      rz2[j*2+0] = (v2f){v[2], v[5]};  rz2[j*2+1] = (v2f){v[8], v[11]};
    } else {
      sX[(j-REG_G)*1024+tid] = make_float4(v[0],v[3],v[6],v[9]);
      sY[(j-REG_G)*1024+tid] = make_float4(v[1],v[4],v[7],v[10]);
      sZ[(j-REG_G)*1024+tid] = make_float4(v[2],v[5],v[8],v[11]);
    }
  }

  float d[32];
#pragma unroll
  for (int i=0;i<32;i++) d[i] = __builtin_huge_valf();

  // first sample = sanitized point 0 (uniform scalar loads)
  float lx = san(pc[bN*3+0]), ly = san(pc[bN*3+1]), lz = san(pc[bN*3+2]);
  if (s==0 && tid<3) g_samp[(size_t)b*KSAMP*3 + tid] = san(pc[bN*3 + tid]);
  __syncthreads();   // LDS coords visible

  const size_t gb = bN + soff + (size_t)7*4096 + tid*4;   // loop-invariant

  for (int k=1; k<KSAMP; k++){
    const int par = k & 1;
    const unsigned long long tagk = (unsigned long long)(unsigned)k << 56;
    // issue global-group loads first (L2-resident region)
    float4 gx = *(const float4*)(g_px+gb);
    float4 gy = *(const float4*)(g_py+gb);
    float4 gz = *(const float4*)(g_pz+gb);

    // broadcast last sample into packed form
    v2f l2x = (v2f){lx,lx}, l2y = (v2f){ly,ly}, l2z = (v2f){lz,lz};

    float bestv = -1.0f; int bestc = 0;   // 5-bit slot code

    // packed distance for a PAIR of points (codes DI, DI+1); scalar tracking in
    // ascending index order preserves the first-max tie-break. pk ops are IEEE
    // rn per half == bit-exact vs the scalar __f*_rn chain.
#define UPD2(X2,Y2,Z2, DI) { \
      v2f dx_ = (X2) - l2x, dy_ = (Y2) - l2y, dz_ = (Z2) - l2z; \
      v2f dd_ = ((dx_*dx_) + (dy_*dy_)) + (dz_*dz_); \
      float nd0_ = fminf(d[DI], dd_.x);  d[DI] = nd0_; \
      if (nd0_ > bestv){ bestv = nd0_; bestc = (DI); } \
      float nd1_ = fminf(d[(DI)+1], dd_.y);  d[(DI)+1] = nd1_; \
      if (nd1_ > bestv){ bestv = nd1_; bestc = (DI)+1; } }

    // register groups j=0..3 (codes 0..15)
#pragma unroll
    for (int p=0;p<REG_G*2;p++)
      UPD2(rx2[p], ry2[p], rz2[p], p*2)
    // LDS groups j=4..6 (codes 16..27)
#pragma unroll
    for (int j=0;j<LDS_G;j++){
      float4 X = sX[j*1024+tid], Y = sY[j*1024+tid], Z = sZ[j*1024+tid];
      v2f Xa=(v2f){X.x,X.y}, Xb=(v2f){X.z,X.w};
      v2f Ya=(v2f){Y.x,Y.y}, Yb=(v2f){Y.z,Y.w};
      v2f Za=(v2f){Z.x,Z.y}, Zb=(v2f){Z.z,Z.w};
      UPD2(Xa, Ya, Za, (REG_G+j)*4)
      UPD2(Xb, Yb, Zb, (REG_G+j)*4+2)
    }
    // global group j=7 (codes 28..31)
    {
      v2f Xa=(v2f){gx.x,gx.y}, Xb=(v2f){gx.z,gx.w};
      v2f Ya=(v2f){gy.x,gy.y}, Yb=(v2f){gy.z,gy.w};
      v2f Za=(v2f){gz.x,gz.y}, Zb=(v2f){gz.z,gz.w};
      UPD2(Xa, Ya, Za, 28)
      UPD2(Xb, Yb, Zb, 30)
    }
#undef UPD2

    // code -> batch-local index (scan order was ascending-index so the
    // first-max tie-break is preserved)
    int besti = soff + ((bestc>>2)<<12) + (tid<<2) + (bestc&3);

    // intra-wave argmax (first-index tie-break)
#pragma unroll
    for (int off=32; off; off>>=1){
      float ov = __shfl_down(bestv, off);
      int   oi = __shfl_down(besti, off);
      if (ov > bestv || (ov == bestv && oi < besti)){ bestv=ov; besti=oi; }
    }
    // key: [val:32][0xFFFFFF^idx:24] — u64 max == (max val, then smallest idx)
    if (lane==0)
      s_cand[wave] = ((unsigned long long)__float_as_uint(bestv) << 24)
                   | (unsigned long long)(0xFFFFFFu ^ (unsigned)besti);

    // barrier #1: orders all 16 candidate stores before wave0's gather; the
    // 15 follower waves fall through to barrier #2 and park there.
    __syncthreads();

    if (wave==0){
      // gather 16 wave candidates (plain LDS loads, barrier-ordered)
      unsigned long long pay = (lane < 16) ? s_cand[lane] : 0ull;
#pragma unroll
      for (int m=1; m<16; m<<=1){
        unsigned long long o = shfl64_xor(pay, m);
        if (o > pay) pay = o;
      }
      // publish block candidate (1 tagged word — the cheap protocol)
      if (lane==0)
        __hip_atomic_store(&g_slot[b][par][s], tagk | pay,
                           __ATOMIC_RELAXED, __HIP_MEMORY_SCOPE_AGENT);
      // tight-poll the 8 slices' slots (lane q watches slice q), WITH in-loop
      // coordinate prefetch: the instant lane q's slot lands, q decodes that
      // slice's candidate index and issues its 3 coord loads (plain L3 loads)
      // while the other lanes keep polling. By butterfly-end the winner's
      // coords are already in flight — the serial ~600-cyc coord fetch leaves
      // the chain. (r8 chain-cut #1)
      unsigned long long gpay = 0;
      float pxl = 0.0f, pyl = 0.0f, pzl = 0.0f;
      if (lane < NBLK_PER_B){
        for (;;){
          unsigned long long gv = __hip_atomic_load(&g_slot[b][par][lane],
                                   __ATOMIC_RELAXED, __HIP_MEMORY_SCOPE_AGENT);
          if ((unsigned)(gv >> 56) == (unsigned)k){
            gpay = gv & PAY56;
            unsigned ci = 0xFFFFFFu ^ (unsigned)(gpay & 0xFFFFFFu);
            const float* cp = pc + (bN + (size_t)ci)*3;
            pxl = cp[0]; pyl = cp[1]; pzl = cp[2];
            break;
          }
        }
      }
      // 8-lane key butterfly (coords stay put; selected by shuffle after)
      unsigned long long gk2 = gpay;
#pragma unroll
      for (int m=1; m<8; m<<=1){
        unsigned long long o = shfl64_xor(gk2, m);
        if (o > gk2) gk2 = o;
      }
      unsigned long long wing = shfl64(gk2, 0);
      unsigned long long gbal = __ballot(lane < NBLK_PER_B && gpay == wing);
      int ws = (int)__ffsll((long long)gbal) - 1;   // winning slice (uniform)
      float wx = san(__shfl(pxl, ws));
      float wy = san(__shfl(pyl, ws));
      float wz = san(__shfl(pzl, ws));
      if (lane < 3)
        s_res[lane] = (lane==0) ? wx : ((lane==1) ? wy : wz);
      // NOTE: g_samp write deferred past barrier #2 (r8 chain-cut #2) — the
      // agent store no longer sits in wave0's vmcnt(0) drain before s_barrier.
    }

    // barrier #2: HW wake; s_res visible after.
    __syncthreads();
    lx = s_res[0]; ly = s_res[1]; lz = s_res[2];

    // off-chain: record the sample during the next compute phase (store drains
    // at the NEXT iteration's barrier #1, ~3000 cyc away).
    if (s==0 && wave==0 && lane<3){
      float cv = (lane==0) ? lx : ((lane==1) ? ly : lz);
      g_samp[((size_t)b*KSAMP + k)*3 + lane] = cv;
    }
  }
}

// ---------------- normalize + Fourier encode ----------------
template<int OP>  // 0 sum, 1 max, 2 min
__device__ __forceinline__ float blk_red(float v, float* s4){
  int tid = threadIdx.x;
#pragma unroll
  for (int off=32; off; off>>=1){
    float o = __shfl_down(v, off);
    v = (OP==0) ? v+o : ((OP==1) ? fmaxf(v,o) : fminf(v,o));
  }
  if ((tid&63)==0) s4[tid>>6] = v;
  __syncthreads();
  float r0=s4[0], r1=s4[1], r2=s4[2], r3=s4[3];
  float r = (OP==0) ? ((r0+r1)+(r2+r3))
          : ((OP==1) ? fmaxf(fmaxf(r0,r1),fmaxf(r2,r3))
                     : fminf(fminf(r0,r1),fminf(r2,r3)));
  __syncthreads();
  return r;
}

__global__ __launch_bounds__(256) void norm_encode(){
  __shared__ float s4[4];
  int b = blockIdx.x, k = threadIdx.x;
  const float* sp = &g_samp[((size_t)b*KSAMP + k)*3];
  float x = sp[0], y = sp[1], z = sp[2];

  float cx = blk_red<0>(x, s4) * (1.0f/KSAMP);
  float cy = blk_red<0>(y, s4) * (1.0f/KSAMP);
  float cz = blk_red<0>(z, s4) * (1.0f/KSAMP);

  float ux = __fsub_rn(x,cx), uy = __fsub_rn(y,cy), uz = __fsub_rn(z,cz);

  float mxx = blk_red<1>(ux, s4), mnx = blk_red<2>(ux, s4);
  float mxy = blk_red<1>(uy, s4), mny = blk_red<2>(uy, s4);
  float mxz = blk_red<1>(uz, s4), mnz = blk_red<2>(uz, s4);
  float bx = __fsub_rn(mxx,mnx), by = __fsub_rn(mxy,mny), bz = __fsub_rn(mxz,mnz);
  float md = fmaxf(fmaxf(bx,by),bz);
  float scale = (md > 1e-8f) ? md : 1.0f;

  float n3[3] = { __fdiv_rn(ux,scale), __fdiv_rn(uy,scale), __fdiv_rn(uz,scale) };

  float* e = &g_enc[((size_t)b*KSAMP + k)*INDIM];
#pragma unroll
  for (int c=0;c<3;c++){
    float base = n3[c];
#pragma unroll
    for (int f=0; f<NF; f++){
      float t = __fmul_rn(base, (float)(1<<f));
      float a = __fmul_rn(t, PI_F);
      e[c*2*NF + f*2 + 0] = sinf(a);
      e[c*2*NF + f*2 + 1] = cosf(a);
    }
  }
}

// ---------------- GEMM ----------------
__global__ __launch_bounds__(256) void gemm_kernel(const float* __restrict__ bias,
                                                   float* __restrict__ out){
  __shared__ float s_enc[4*INDIM];
  int blk = blockIdx.x, tid = threadIdx.x;
  int row0 = blk*4;                         // 4 (b,k) rows per block
  if (tid < 4*INDIM) s_enc[tid] = g_enc[(size_t)row0*INDIM + tid];
  __syncthreads();

  float acc[4][3] = {};
  for (int d=0; d<INDIM; d++){
    float w0 = g_Wt[d*HID + tid];
    float w1 = g_Wt[d*HID + tid + 256];
    float w2 = g_Wt[d*HID + tid + 512];
#pragma unroll
    for (int r=0;r<4;r++){
      float ev = s_enc[r*INDIM + d];
      acc[r][0] = fmaf(ev, w0, acc[r][0]);
      acc[r][1] = fmaf(ev, w1, acc[r][1]);
      acc[r][2] = fmaf(ev, w2, acc[r][2]);
    }
  }
  float b0=bias[tid], b1=bias[tid+256], b2=bias[tid+512];
#pragma unroll
  for (int r=0;r<4;r++){
    size_t o = (size_t)(row0+r)*HID;
    out[o+tid]     = acc[r][0]+b0;
    out[o+tid+256] = acc[r][1]+b1;
    out[o+tid+512] = acc[r][2]+b2;
  }
}

// ---------------- launch ----------------
extern "C" void kernel_launch(void* const* d_in, const int* in_sizes, int n_in,
                              void* d_out, int out_size, void* d_ws, size_t ws_size,
                              hipStream_t stream){
  const float* pc   = (const float*)d_in[0];
  const float* W    = (const float*)d_in[1];
  const float* bias = (const float*)d_in[2];
  float* out = (float*)d_out;

  region_prepass<<<1024, 256, 0, stream>>>(pc);
  wtrans        <<<(INDIM*HID)/256, 256, 0, stream>>>(W);

  void* args[] = { (void*)&pc };
  hipLaunchCooperativeKernel((void*)fps_kernel, dim3(BATCH*NBLK_PER_B), dim3(1024),
                             args, 0, stream);

  norm_encode<<<BATCH, KSAMP, 0, stream>>>();
  gemm_kernel<<<(BATCH*KSAMP)/4, 256, 0, stream>>>(bias, out);
}